// Round 5
// baseline (64.963 us; speedup 1.0000x reference)
//
#include <hip/hip_runtime.h>
#include <math.h>

#define B_ 4
#define C_ 2048
#define T_ 8192
#define TT 8                 // t-tiles per b
#define TSPAN 1024           // t columns per block (4KB per row)
#define NCH 4                // 256-col chunks per row (TSPAN/256)
#define CS 16                // C splits
#define CROWS (C_ / CS)      // 128 rows per block
#define NW 8                 // waves per block
#define RW (CROWS / NW)      // 16 rows per wave
#define RT 4                 // rows per tile (in flight)

typedef float f4 __attribute__((ext_vector_type(4)));

#define WS_ACC  ((size_t)B_ * T_ * CS * 8)   // partial = 4 MiB of float2
#define WS_DONE (WS_ACC + 32)

constexpr float Kc   = 30.0f * 1.4426950408889634f;          // S*log2(e)
constexpr float MM2  = 30.0f * 0.4f * 1.4426950408889634f;   // S*M*log2(e)
constexpr float LN2f = 0.6931471805599453f;

// K1: block = (b, tt, cs) covers 128 rows x 1024 t-cols. Waves split rows;
// each wave reads 4KB contiguous per row, 4 rows per tile (16 loads in
// flight), online lse in log2 domain with 4-row group max. Cross-wave merge
// in 4 LDS rounds; per-(b,t,cs) float2 (m,S) partial to ws.
__global__ __launch_bounds__(512, 4)
void adms_partial(const float* __restrict__ logits,
                  float2* __restrict__ partial,
                  float* __restrict__ accum,
                  unsigned* __restrict__ done)
{
    if (blockIdx.x == 0 && threadIdx.x == 0) {
        #pragma unroll
        for (int k = 0; k < 8; ++k) accum[k] = 0.f;
        *done = 0u;
    }

    const int lane = threadIdx.x & 63;
    const int w    = threadIdx.x >> 6;
    const int cs = blockIdx.x & (CS - 1);
    const int tt = (blockIdx.x >> 4) & (TT - 1);
    const int b  = blockIdx.x >> 7;

    const int t0 = tt * TSPAN;
    const int c0 = cs * CROWS + w * RW;
    const float* p = logits + (size_t)(b * C_ + c0) * T_ + t0 + lane * 4;

    float m[NCH][4], s[NCH][4];
    #pragma unroll
    for (int c = 0; c < NCH; ++c)
        #pragma unroll
        for (int j = 0; j < 4; ++j) { m[c][j] = -INFINITY; s[c][j] = 0.f; }

    for (int rt = 0; rt < RW; rt += RT) {
        f4 v[RT][NCH];
        #pragma unroll
        for (int r = 0; r < RT; ++r)
            #pragma unroll
            for (int c = 0; c < NCH; ++c)
                v[r][c] = *(const f4*)(p + (size_t)(rt + r) * T_ + c * 256);
        #pragma unroll
        for (int c = 0; c < NCH; ++c)
            #pragma unroll
            for (int j = 0; j < 4; ++j) {
                float g = fmaxf(fmaxf(v[0][c][j], v[1][c][j]),
                                fmaxf(v[2][c][j], v[3][c][j]));
                float n = fmaxf(m[c][j], g);
                float nK = n * Kc;
                float ps =       exp2f(fmaf(v[0][c][j], Kc, -nK));
                ps       +=      exp2f(fmaf(v[1][c][j], Kc, -nK));
                ps       +=      exp2f(fmaf(v[2][c][j], Kc, -nK));
                ps       +=      exp2f(fmaf(v[3][c][j], Kc, -nK));
                s[c][j] = fmaf(s[c][j], exp2f(fmaf(m[c][j], Kc, -nK)), ps);
                m[c][j] = n;
            }
    }

    // cross-wave merge: 4 rounds of 256 t-cols
    __shared__ float2 lds2[NW][256];
    #pragma unroll
    for (int g = 0; g < NCH; ++g) {
        #pragma unroll
        for (int j = 0; j < 4; ++j)
            lds2[w][lane * 4 + j] = make_float2(m[g][j], s[g][j]);
        __syncthreads();
        if (threadIdx.x < 256) {
            const int tc = threadIdx.x;
            float M = -INFINITY;
            float2 e[NW];
            #pragma unroll
            for (int k = 0; k < NW; ++k) { e[k] = lds2[k][tc]; M = fmaxf(M, e[k].x); }
            const float MK = M * Kc;
            float S = 0.f;
            #pragma unroll
            for (int k = 0; k < NW; ++k)
                S = fmaf(e[k].y, exp2f(fmaf(e[k].x, Kc, -MK)), S);
            const size_t t = (size_t)t0 + g * 256 + tc;
            partial[((size_t)b * T_ + t) * CS + cs] = make_float2(M, S);
        }
        __syncthreads();
    }
}

// K2: merge 16 partials per (b,t) (128B contiguous per thread), gather the
// label logit, margin fixup, per-b reduce, last-block finalize.
__global__ __launch_bounds__(256)
void adms_merge(const float* __restrict__ logits,
                const int* __restrict__ target,
                const float2* __restrict__ partial,
                float* __restrict__ accum,
                unsigned* __restrict__ done,
                float* __restrict__ out,
                int nblocks)
{
    const int idx = blockIdx.x * 256 + threadIdx.x;   // 0..32767
    const int b = idx >> 13;
    const int t = idx & (T_ - 1);

    const float2* pf = partial + (size_t)idx * CS;
    float2 q[CS];
    float M = -INFINITY;
    #pragma unroll
    for (int k = 0; k < CS; ++k) { q[k] = pf[k]; M = fmaxf(M, q[k].x); }
    const float MK = M * Kc;
    float S = 0.f;
    #pragma unroll
    for (int k = 0; k < CS; ++k)
        S = fmaf(q[k].y, exp2f(fmaf(q[k].x, Kc, -MK)), S);

    const int raw = target[idx];
    const bool valid = (raw != -1);
    const int lbl = valid ? raw : 0;
    const float wl = logits[(size_t)(b * C_ + lbl) * T_ + t];

    // swap label term exp2(wl*K - MK) for exp2(wl*K - MK - MM2)
    const float el = exp2f(fmaf(wl, Kc, -MK));
    float Smod = fmaf(-el, 1.0f - exp2f(-MM2), S);
    Smod = fmaxf(Smod, 1e-35f);
    const float L = (fmaf(wl, Kc, -MK) - MM2 - log2f(Smod)) * LN2f;

    float contrib = valid ? -L : 0.f;
    float cnt     = valid ? 1.f : 0.f;
    #pragma unroll
    for (int off = 32; off; off >>= 1) {
        contrib += __shfl_down(contrib, off);
        cnt     += __shfl_down(cnt, off);
    }

    __shared__ float wsum[4], wcnt[4];
    const int lane = threadIdx.x & 63, w = threadIdx.x >> 6;
    if (lane == 0) { wsum[w] = contrib; wcnt[w] = cnt; }
    __syncthreads();

    if (threadIdx.x == 0) {
        float cs_ = 0.f, cc = 0.f;
        #pragma unroll
        for (int k = 0; k < 4; ++k) { cs_ += wsum[k]; cc += wcnt[k]; }
        const int bb = blockIdx.x >> 5;   // 32 blocks per b
        atomicAdd(&accum[bb], cs_);
        atomicAdd(&accum[4 + bb], cc);
        __threadfence();
        const unsigned old = atomicAdd(done, 1u);
        if (old == (unsigned)(nblocks - 1)) {
            float acc = 0.f;
            #pragma unroll
            for (int k = 0; k < B_; ++k) {
                const float ss = atomicAdd(&accum[k], 0.f);
                const float sc = atomicAdd(&accum[4 + k], 0.f);
                acc += ss / sc;
            }
            out[0] = acc * (1.0f / (float)B_);
        }
    }
}

extern "C" void kernel_launch(void* const* d_in, const int* in_sizes, int n_in,
                              void* d_out, int out_size, void* d_ws, size_t ws_size,
                              hipStream_t stream) {
    const float* logits = (const float*)d_in[0];
    const int*   target = (const int*)d_in[1];
    float*    out     = (float*)d_out;
    float2*   partial = (float2*)d_ws;
    float*    accum   = (float*)((char*)d_ws + WS_ACC);
    unsigned* done    = (unsigned*)((char*)d_ws + WS_DONE);

    adms_partial<<<B_ * TT * CS, 512, 0, stream>>>(logits, partial, accum, done);

    const int nb2 = (B_ * T_) / 256;   // 128
    adms_merge<<<nb2, 256, 0, stream>>>(logits, target, partial, accum, done, out, nb2);
}